// Round 2
// baseline (110.090 us; speedup 1.0000x reference)
//
#include <hip/hip_runtime.h>

#define NX 512
#define NY 512
#define NZ 64
#define NCELL (NX * NY * NZ)   // 16,777,216
#define SX (NY * NZ)           // 32768 floats
#define SY (NZ)                // 64 floats
#define LRUN 8                 // x-cells walked per thread
#define NBLK 2048              // (NX/LRUN)*NY*(NZ/4) / 256

typedef float f4 __attribute__((ext_vector_type(4)));

// Summed per-cell term (pairs folded, x2 absorbed into scale):
//   T(i) = mz(i)*mx(i-ex) - mx(i)*mz(i-ex) + mz(i)*my(i-ey) - my(i)*mz(i-ey)
// out = D * CELLSIZE2 * sum(T) / NCELL

__global__ __launch_bounds__(256) void dmi_fused(const float* __restrict__ x,
                                                 const float* __restrict__ D,
                                                 float* __restrict__ out,
                                                 float* __restrict__ ws,
                                                 unsigned int* __restrict__ counter) {
    const float* mx = x;
    const float* my = x + NCELL;
    const float* mz = x + 2 * NCELL;

    int t   = blockIdx.x * 256 + threadIdx.x;
    int iz4 = t & 15;
    int iy  = (t >> 4) & 511;
    int cx  = t >> 13;                       // x-chunk index, 0..63
    int off = cx * (LRUN * SX) + iy * SY + (iz4 << 2);

    // previous-x plane values carried in registers
    f4 px, pz;
    if (cx > 0) {
        px = *(const f4*)(mx + off - SX);
        pz = *(const f4*)(mz + off - SX);
    } else {
        px = (f4)(0.0f);                      // ix==0 has no x-neighbor term
        pz = (f4)(0.0f);
    }

    const bool has_y = (iy > 0);
    float acc = 0.0f;
#pragma unroll
    for (int j = 0; j < LRUN; ++j, off += SX) {
        f4 ax = *(const f4*)(mx + off);
        f4 ay = *(const f4*)(my + off);
        f4 az = *(const f4*)(mz + off);
        f4 tv = az * px - ax * pz;
        if (has_y) {
            f4 by = *(const f4*)(my + off - SY);
            f4 bz = *(const f4*)(mz + off - SY);
            tv += az * by - ay * bz;
        }
        acc += tv[0] + tv[1] + tv[2] + tv[3];
        px = ax;
        pz = az;
    }

    // wave64 reduce, then block reduce
    for (int o = 32; o > 0; o >>= 1) acc += __shfl_down(acc, o);

    __shared__ float sacc[4];
    __shared__ int lastFlag;
    int lane = threadIdx.x & 63;
    int wid  = threadIdx.x >> 6;
    if (lane == 0) sacc[wid] = acc;
    __syncthreads();

    if (threadIdx.x == 0) {
        float p = sacc[0] + sacc[1] + sacc[2] + sacc[3];
        atomicExch(&ws[blockIdx.x], p);       // device-scope store of partial
        __threadfence();
        unsigned prev = atomicAdd(counter, 1u);
        lastFlag = (prev == NBLK - 1) ? 1 : 0;
    }
    __syncthreads();

    if (lastFlag) {
        __threadfence();
        double d = 0.0;
        for (int i = threadIdx.x; i < NBLK; i += 256)
            d += (double)atomicAdd(&ws[i], 0.0f);   // device-scope load
        for (int o = 32; o > 0; o >>= 1) d += __shfl_down(d, o);

        __shared__ double dacc[4];
        if (lane == 0) dacc[wid] = d;
        __syncthreads();
        if (threadIdx.x == 0) {
            double total = dacc[0] + dacc[1] + dacc[2] + dacc[3];
            double scale = (double)D[0] * 4e-18 / (double)NCELL;  // CELLSIZE2=(2e-9)^2
            out[0] = (float)(total * scale);
        }
    }
}

extern "C" void kernel_launch(void* const* d_in, const int* in_sizes, int n_in,
                              void* d_out, int out_size, void* d_ws, size_t ws_size,
                              hipStream_t stream) {
    const float* x = (const float*)d_in[0];
    // d_in[1] = geo (unused by forward)
    const float* D = (const float*)d_in[2];
    float* out = (float*)d_out;
    float* ws  = (float*)d_ws;
    unsigned int* counter = (unsigned int*)((char*)d_ws + NBLK * sizeof(float));

    hipMemsetAsync(counter, 0, sizeof(unsigned int), stream);
    dmi_fused<<<NBLK, 256, 0, stream>>>(x, D, out, ws, counter);
}

// Round 3
// 38.606 us; speedup vs baseline: 2.8516x; 2.8516x over previous
//
#include <hip/hip_runtime.h>

#define NX 512
#define NY 512
#define NZ 64
#define NCELL (NX * NY * NZ)          // 16,777,216
#define NG4   (NX * NY * (NZ / 4))   // 4,194,304 float4 groups
#define STRIDE_X (NY * NZ)           // 32768 floats
#define STRIDE_Y (NZ)                // 64 floats
#define NBLK 2048
#define NTHREADS (NBLK * 256)        // 524,288
#define ITERS (NG4 / NTHREADS)       // 8

typedef float f4 __attribute__((ext_vector_type(4)));

// Summed per-cell term (±neighbor pairs folded; factor 2 absorbed into scale):
//   T(i) = mz(i)*mx(i-ex) - mx(i)*mz(i-ex) + mz(i)*my(i-ey) - my(i)*mz(i-ey)
// out = D * CELLSIZE2 * sum(T) / NCELL

__global__ __launch_bounds__(256) void dmi_partial(const float* __restrict__ x,
                                                   float* __restrict__ ws) {
    const float* mx = x;
    const float* my = x + NCELL;
    const float* mz = x + 2 * NCELL;

    float acc = 0.0f;
    int tid = blockIdx.x * 256 + threadIdx.x;

#pragma unroll 2
    for (int k = 0; k < ITERS; ++k) {
        int g = tid + k * NTHREADS;            // whole-GPU linear sweep
        int iz4 = g & 15;
        int iy  = (g >> 4) & 511;
        int ix  = g >> 13;
        int off = (ix << 15) + (iy << 6) + (iz4 << 2);  // floats

        f4 ax = *(const f4*)(mx + off);
        f4 ay = *(const f4*)(my + off);
        f4 az = *(const f4*)(mz + off);

        f4 t = (f4)(0.0f);
        if (ix > 0) {
            f4 bx = *(const f4*)(mx + off - STRIDE_X);
            f4 bz = *(const f4*)(mz + off - STRIDE_X);
            t += az * bx - ax * bz;
        }
        if (iy > 0) {
            f4 by = *(const f4*)(my + off - STRIDE_Y);
            f4 bz = *(const f4*)(mz + off - STRIDE_Y);
            t += az * by - ay * bz;
        }
        acc += t[0] + t[1] + t[2] + t[3];
    }

    // wave64 reduce, then block reduce (deterministic tree)
    for (int o = 32; o > 0; o >>= 1) acc += __shfl_down(acc, o);

    __shared__ float sacc[4];
    int lane = threadIdx.x & 63;
    int wid  = threadIdx.x >> 6;
    if (lane == 0) sacc[wid] = acc;
    __syncthreads();
    if (threadIdx.x == 0)
        ws[blockIdx.x] = sacc[0] + sacc[1] + sacc[2] + sacc[3];
}

__global__ __launch_bounds__(256) void dmi_final(const float* __restrict__ ws,
                                                 const float* __restrict__ D,
                                                 float* __restrict__ out) {
    // 2048 partials = 256 threads x 2 float4
    const f4* w4 = (const f4*)ws;
    f4 a = w4[threadIdx.x];
    f4 b = w4[threadIdx.x + 256];
    double acc = (double)a[0] + a[1] + a[2] + a[3]
               + (double)b[0] + b[1] + b[2] + b[3];

    for (int o = 32; o > 0; o >>= 1) acc += __shfl_down(acc, o);

    __shared__ double sacc[4];
    int lane = threadIdx.x & 63;
    int wid  = threadIdx.x >> 6;
    if (lane == 0) sacc[wid] = acc;
    __syncthreads();
    if (threadIdx.x == 0) {
        double total = sacc[0] + sacc[1] + sacc[2] + sacc[3];
        double scale = (double)D[0] * 4e-18 / (double)NCELL;  // CELLSIZE2=(2e-9)^2
        out[0] = (float)(total * scale);
    }
}

extern "C" void kernel_launch(void* const* d_in, const int* in_sizes, int n_in,
                              void* d_out, int out_size, void* d_ws, size_t ws_size,
                              hipStream_t stream) {
    const float* x = (const float*)d_in[0];
    // d_in[1] = geo (unused by forward)
    const float* D = (const float*)d_in[2];
    float* out = (float*)d_out;
    float* ws  = (float*)d_ws;

    dmi_partial<<<NBLK, 256, 0, stream>>>(x, ws);
    dmi_final<<<1, 256, 0, stream>>>(ws, D, out);
}